// Round 11
// baseline (169.962 us; speedup 1.0000x reference)
//
#include <hip/hip_runtime.h>

typedef short bf16x8 __attribute__((ext_vector_type(8)));
typedef short bf16x4 __attribute__((ext_vector_type(4)));
typedef float f32x4 __attribute__((ext_vector_type(4)));

__device__ inline float bf2f(ushort u) {
    unsigned v = ((unsigned)u) << 16;
    return __builtin_bit_cast(float, v);
}
__device__ inline ushort f2bf(float f) {
    unsigned u = __builtin_bit_cast(unsigned, f);
    u += 0x7fffu + ((u >> 16) & 1u);
    return (ushort)(u >> 16);
}
__device__ inline void async_load16(const ushort* g, ushort* l) {
    __builtin_amdgcn_global_load_lds((const __attribute__((address_space(1))) void*)g,
                                     (__attribute__((address_space(3))) void*)l, 16, 0, 0);
}
// K=16 bf16 MFMA: A[m=l15][k=quad*4+j] == our P C-layout -> PV needs NO transpose.
__device__ inline f32x4 mfma16(bf16x4 a, bf16x4 b, f32x4 c) {
#if __has_builtin(__builtin_amdgcn_mfma_f32_16x16x16_bf16)
    return __builtin_amdgcn_mfma_f32_16x16x16_bf16(a, b, c, 0, 0, 0);
#else
    return __builtin_amdgcn_mfma_f32_16x16x16bf16_1k(a, b, c, 0, 0, 0);
#endif
}

// Single merged fp32->bf16 cast for all 5 tensors. 8 elems/thread.
__global__ void cast_all(const float* __restrict__ hs, const float* __restrict__ Wq,
                         const float* __restrict__ Wk, const float* __restrict__ Wv,
                         const float* __restrict__ Ws,
                         ushort* __restrict__ dhs, ushort* __restrict__ dWq,
                         ushort* __restrict__ dWk, ushort* __restrict__ dWv,
                         ushort* __restrict__ dWs)
{
    int bid = blockIdx.x;
    const float* src; ushort* dst; int off;
    if (bid < 2048)      { src = hs; dst = dhs; off = bid; }
    else if (bid < 2560) { src = Wq; dst = dWq; off = bid - 2048; }
    else if (bid < 3072) { src = Wk; dst = dWk; off = bid - 2560; }
    else if (bid < 3584) { src = Wv; dst = dWv; off = bid - 3072; }
    else                 { src = Ws; dst = dWs; off = bid - 3584; }
    int i = (off * 256 + threadIdx.x) * 8;
    float4 a = *(const float4*)(src + i);
    float4 b = *(const float4*)(src + i + 4);
    union { ushort u[8]; float4 v; } o;
    o.u[0] = f2bf(a.x); o.u[1] = f2bf(a.y); o.u[2] = f2bf(a.z); o.u[3] = f2bf(a.w);
    o.u[4] = f2bf(b.x); o.u[5] = f2bf(b.y); o.u[6] = f2bf(b.z); o.u[7] = f2bf(b.w);
    *(float4*)(dst + i) = o.v;
}

// Fused QKVS projection (unchanged). X:[4096,1024] bf16, W*:[N,1024] bf16, bias fp32.
// xb 0-7 -> Q (scaled 0.125*log2e), 8-15 -> K, 16-23 -> V (transposed to VtG[bh][d][s]),
// 24-25 -> S (sigmoid -> fp32 sb). LDS XOR chunk swizzle: chunk c of row r at slot c^(r&7).
__launch_bounds__(256, 4)
__global__ void fused_qkvs(const ushort* __restrict__ X,
                           const ushort* __restrict__ Wq, const ushort* __restrict__ Wk,
                           const ushort* __restrict__ Wv, const ushort* __restrict__ Ws,
                           const float* __restrict__ bq, const float* __restrict__ bk,
                           const float* __restrict__ bv, const float* __restrict__ bs,
                           ushort* __restrict__ Qb, ushort* __restrict__ Kb,
                           ushort* __restrict__ VtG, float* __restrict__ sb)
{
    __shared__ __align__(16) ushort Sm[128 * 136];
    ushort* As = Sm;
    ushort* Bs = Sm + 128 * 64;

    const int tid = threadIdx.x, w = tid >> 6, lane = tid & 63;
    const int l15 = lane & 15, quad = lane >> 4;
    const int lrow = lane >> 3;
    const int gchunk = ((lane & 7) ^ lrow) * 8;

    const int wid = blockIdx.x;
    const int r8 = wid & 7, jj = wid >> 3;
    const int by = (jj & 3) * 8 + r8;
    const int xb = jj >> 2;
    const int m0 = by * 128;

    const ushort* W; const float* bias; int n0, mode;
    if (xb < 8)       { W = Wq; bias = bq; n0 = xb * 128;        mode = 1; }
    else if (xb < 16) { W = Wk; bias = bk; n0 = (xb - 8) * 128;  mode = 0; }
    else if (xb < 24) { W = Wv; bias = bv; n0 = (xb - 16) * 128; mode = 2; }
    else              { W = Ws; bias = bs; n0 = (xb - 24) * 128; mode = 3; }

    const int wm = (w >> 1) * 64, wn = (w & 1) * 64;

    f32x4 acc[4][4];
    for (int i = 0; i < 4; i++) for (int j = 0; j < 4; j++) acc[i][j] = (f32x4){0.f, 0.f, 0.f, 0.f};

    for (int k0 = 0; k0 < 1024; k0 += 64) {
        __syncthreads();
        for (int c = 0; c < 4; ++c) {
            int r = w * 32 + c * 8;
            async_load16(&X[(size_t)(m0 + r + lrow) * 1024 + k0 + gchunk], &As[r * 64]);
            async_load16(&W[(size_t)(n0 + r + lrow) * 1024 + k0 + gchunk], &Bs[r * 64]);
        }
        __syncthreads();
        for (int kk = 0; kk < 64; kk += 32) {
            const int csw = quad + (kk >> 3);
            bf16x8 a[4], b[4];
            for (int i = 0; i < 4; i++)
                a[i] = *(const bf16x8*)&As[(wm + i * 16 + l15) * 64 + ((csw ^ (l15 & 7)) * 8)];
            for (int j = 0; j < 4; j++)
                b[j] = *(const bf16x8*)&Bs[(wn + j * 16 + l15) * 64 + ((csw ^ (l15 & 7)) * 8)];
            for (int i = 0; i < 4; i++)
                for (int j = 0; j < 4; j++)
                    acc[i][j] = __builtin_amdgcn_mfma_f32_16x16x32_bf16(a[i], b[j], acc[i][j], 0, 0, 0);
        }
    }

    const float QSCALE = 0.125f * 1.44269504f;

    if (mode == 3) {
        for (int i = 0; i < 4; i++)
            for (int j = 0; j < 4; j++) {
                int gn = n0 + wn + j * 16 + l15;
                float bv_ = bias[gn];
                for (int r = 0; r < 4; r++) {
                    int gm = m0 + wm + i * 16 + quad * 4 + r;
                    float v = acc[i][j][r] + bv_;
                    float sg = __builtin_amdgcn_rcpf(1.0f + __builtin_amdgcn_exp2f(-v * 1.44269504f));
                    sb[(size_t)gm * 256 + gn] = sg * 0.1f + 0.95f;
                }
            }
        return;
    }

    __syncthreads();

    if (mode == 2) {
        for (int i = 0; i < 4; i++)
            for (int j = 0; j < 4; j++) {
                int gnl = wn + j * 16 + l15;
                float bv_ = bias[n0 + gnl];
                ushort4 pk;
                pk.x = f2bf(acc[i][j][0] + bv_);
                pk.y = f2bf(acc[i][j][1] + bv_);
                pk.z = f2bf(acc[i][j][2] + bv_);
                pk.w = f2bf(acc[i][j][3] + bv_);
                *(ushort4*)&Sm[gnl * 136 + wm + i * 16 + quad * 4] = pk;
            }
        __syncthreads();
        const int bb = m0 >> 11, sloc = m0 & 2047;
        for (int it = 0; it < 8; ++it) {
            int d = (tid >> 4) + it * 16;
            int s8 = (tid & 15) * 8;
            float4 v = *(float4*)&Sm[d * 136 + s8];
            int h = (n0 + d) >> 6, dd = d & 63;
            *(float4*)&VtG[(size_t)(bb * 16 + h) * 131072 + (size_t)dd * 2048 + sloc + s8] = v;
        }
    } else {
        for (int i = 0; i < 4; i++)
            for (int j = 0; j < 4; j++) {
                int gnl = wn + j * 16 + l15;
                float bv_ = bias[n0 + gnl];
                for (int r = 0; r < 4; r++) {
                    float v = acc[i][j][r] + bv_;
                    if (mode == 1) v *= QSCALE;
                    Sm[(wm + i * 16 + quad * 4 + r) * 136 + gnl] = f2bf(v);
                }
            }
        __syncthreads();
        ushort* dst = (mode == 1) ? Qb : Kb;
        for (int it = 0; it < 8; ++it) {
            int row = (tid >> 4) + it * 16, c = (tid & 15) * 8;
            *(float4*)&dst[(size_t)(m0 + row) * 1024 + n0 + c] = *(float4*)&Sm[row * 136 + c];
        }
    }
}

// Flash attention v22: v21 (K16-PV + mt=2, 54.0us verified) with the serial structure
// attacked: (a) KVBLK=128 -- K/V tiles staged as two stacked 64-sub-tiles (+sub*4096;
// all swizzle/frag formulas unchanged), halving barriers 32->16 so each vmcnt drain
// amortizes over 2x compute; (b) Q frags loaded directly from global into registers
// (B-32 layout cols cbase+kk2*32+quad*8 are 16B-contiguous in Q; scale math
// bit-identical to the old staged path) -- deletes the Qs LDS region, its staging
// loop, and one prologue barrier. LDS 48KB->64KB (2 blocks/CU = grid/CU, unchanged).
__launch_bounds__(256, 2)
__global__ void attn_kernel(const ushort* __restrict__ Q, const ushort* __restrict__ K,
                            const ushort* __restrict__ Vt, const float* __restrict__ sb,
                            float* __restrict__ out)
{
    __shared__ __align__(16) ushort SmA[4 * 8192];   // 64KB: Ks0|Ks1|Vs0|Vs1 (16KB each)
    ushort* Ks0 = SmA;
    ushort* Ks1 = SmA + 8192;
    ushort* Vs0 = SmA + 16384;
    ushort* Vs1 = SmA + 24576;

    const int tid = threadIdx.x, w = tid >> 6, lane = tid & 63;
    const int l15 = lane & 15, quad = lane >> 4;
    const int lrow = lane >> 3;
    const int gchunk = ((lane & 7) ^ lrow) * 8;

    // XCD swizzle: same bh (same K/V) -> same XCD
    const int wid = blockIdx.x;                  // 0..511
    const int r8 = wid & 7, jj = wid >> 3;       // jj 0..63
    const int bh = (jj & 3) * 8 + r8;            // 0..31
    const int qx = jj >> 2;                      // 0..15
    const int b = bh >> 4, h = bh & 15;
    const int q0 = qx * 128;
    const size_t rowbase = (size_t)b * 2048;
    const int cbase = h * 64;

    // global staging bases (per-thread, loop-invariant)
    // K: each wave stages 32 key-rows per 128-tile (c=0..3 -> +8 rows each)
    const ushort* kg = K + (rowbase + w * 32 + lrow) * 1024 + cbase + gchunk;
    // V: each wave stages 16 d-rows x two 64-s chunks per 128-tile
    const ushort* vg = Vt + (size_t)bh * 131072 + (size_t)(w * 16 + lrow) * 2048 + gchunk;

    // prefetch K/V tile 0 (128 keys)
    for (int c = 0; c < 4; ++c)
        async_load16(kg + c * 8192, Ks0 + w * 2048 + c * 512);
    for (int ss = 0; ss < 2; ++ss)
        for (int c = 0; c < 2; ++c)
            async_load16(vg + ss * 64 + c * 16384, Vs0 + ss * 4096 + w * 1024 + c * 512);

    // Q frags direct from global (B-32 layout: row=q, cols cbase+kk2*32+quad*8..+7),
    // applying groupwise scale s (2 groups of 4 per 8 cols) -- bit-identical math.
    bf16x8 aq[2][2];  // [mt][kk2]
    for (int mt = 0; mt < 2; mt++)
        for (int kk2 = 0; kk2 < 2; kk2++) {
            size_t qrow = rowbase + q0 + w * 32 + mt * 16 + l15;
            int c0 = cbase + kk2 * 32 + quad * 8;
            union { float4 f; ushort u[8]; } uu;
            union { ushort u[8]; bf16x8 v; } oo;
            uu.f = *(const float4*)&Q[qrow * 1024 + c0];
            const float* sp = &sb[qrow * 256 + (c0 >> 2)];
            float s0 = sp[0], s1 = sp[1];
            for (int j = 0; j < 4; j++) oo.u[j] = f2bf(bf2f(uu.u[j]) * s0);
            for (int j = 4; j < 8; j++) oo.u[j] = f2bf(bf2f(uu.u[j]) * s1);
            aq[mt][kk2] = oo.v;
        }

    // precomputed loop-invariant LDS offsets (within a 64-sub-tile)
    int kvoff[2][4];   // K frags (A-32 layout)
    for (int kk2 = 0; kk2 < 2; kk2++)
        for (int nt = 0; nt < 4; nt++)
            kvoff[kk2][nt] = (nt * 16 + l15) * 64 + (((quad + kk2 * 4) ^ (l15 & 7)) * 8);
    // V frags (B-16 layout): row d = nt*16+l15, keys kt2*16+quad*4+{0..3}
    int vaddr[4];
    for (int kt2 = 0; kt2 < 4; kt2++)
        vaddr[kt2] = l15 * 64 + (quad & 1) * 4
                   + (((kt2 * 2 + (quad >> 1)) ^ (l15 & 7)) * 8);

    // all-ones bf16 B-frag (K=16): osum = P @ 1 gives per-q-row softmax denominators
    const bf16x4 vones4 = {0x3F80, 0x3F80, 0x3F80, 0x3F80};

    f32x4 osum[2];
    f32x4 o[2][4];
    for (int mt = 0; mt < 2; mt++) {
        osum[mt] = (f32x4){0.f, 0.f, 0.f, 0.f};
        for (int nt = 0; nt < 4; nt++) o[mt][nt] = (f32x4){0.f, 0.f, 0.f, 0.f};
    }
    const f32x4 z4 = (f32x4){0.f, 0.f, 0.f, 0.f};

// One 128-key macro-step: barrier, prefetch next 128-tile, compute 2 x 64-sub-tiles.
#define ATTN_STEP(KC, VC, KN, VN, KT, PREFETCH)                                                         \
    {                                                                                                   \
        __syncthreads(); /* vmcnt+lgkm drained: tile KT resident; buffers KN/VN free */                 \
        if (PREFETCH) {                                                                                 \
            const int nk = (KT) + 1;                                                                    \
            for (int c = 0; c < 4; ++c)                                                                 \
                async_load16(kg + (size_t)nk * 131072 + c * 8192, KN + w * 2048 + c * 512);             \
            for (int ss = 0; ss < 2; ++ss)                                                              \
                for (int c = 0; c < 2; ++c)                                                             \
                    async_load16(vg + nk * 128 + ss * 64 + c * 16384,                                   \
                                 VN + ss * 4096 + w * 1024 + c * 512);                                  \
        }                                                                                               \
        _Pragma("unroll")                                                                               \
        for (int sub = 0; sub < 2; ++sub) {                                                             \
            const ushort* KCs = KC + sub * 4096;                                                        \
            const ushort* VCs = VC + sub * 4096;                                                        \
            bf16x8 kb[2][4];                                                                            \
            for (int kk2 = 0; kk2 < 2; kk2++)                                                           \
                for (int nt = 0; nt < 4; nt++)                                                          \
                    kb[kk2][nt] = *(const bf16x8*)&KCs[kvoff[kk2][nt]];                                 \
            bf16x4 vb4[4][4];                                                                           \
            _Pragma("unroll")                                                                           \
            for (int kt2 = 0; kt2 < 4; kt2++)                                                           \
                _Pragma("unroll")                                                                       \
                for (int nt = 0; nt < 4; nt++)                                                          \
                    vb4[kt2][nt] = *(const bf16x4*)&VCs[vaddr[kt2] + nt * 1024];                        \
            _Pragma("unroll")                                                                           \
            for (int mt = 0; mt < 2; mt++) {                                                            \
                /* S^T: A = K frag (m=key), B = Q frag (n=q-row) */                                     \
                f32x4 st[4];                                                                            \
                _Pragma("unroll")                                                                       \
                for (int kt2 = 0; kt2 < 4; kt2++) {                                                     \
                    st[kt2] = __builtin_amdgcn_mfma_f32_16x16x32_bf16(kb[0][kt2], aq[mt][0],            \
                                                                      z4, 0, 0, 0);                     \
                    st[kt2] = __builtin_amdgcn_mfma_f32_16x16x32_bf16(kb[1][kt2], aq[mt][1],            \
                                                                      st[kt2], 0, 0, 0);                \
                }                                                                                       \
                /* exp + pack: du0=(r0,r1), du1=(r2,r3) -> directly the K=16 A-frag dwords */           \
                unsigned du0[4], du1[4];                                                                \
                _Pragma("unroll")                                                                       \
                for (int kt2 = 0; kt2 < 4; kt2++) {                                                     \
                    float p0 = __builtin_amdgcn_exp2f(st[kt2][0]);                                      \
                    float p1 = __builtin_amdgcn_exp2f(st[kt2][1]);                                      \
                    float p2 = __builtin_amdgcn_exp2f(st[kt2][2]);                                      \
                    float p3 = __builtin_amdgcn_exp2f(st[kt2][3]);                                      \
                    du0[kt2] = __builtin_amdgcn_perm(__builtin_bit_cast(unsigned, p1) + 0x8000u,        \
                                                     __builtin_bit_cast(unsigned, p0) + 0x8000u,        \
                                                     0x07060302u);                                      \
                    du1[kt2] = __builtin_amdgcn_perm(__builtin_bit_cast(unsigned, p3) + 0x8000u,        \
                                                     __builtin_bit_cast(unsigned, p2) + 0x8000u,        \
                                                     0x07060302u);                                      \
                }                                                                                       \
                /* O += P @ V via K=16 MFMA: A-frag = held C-layout, zero data movement */              \
                _Pragma("unroll")                                                                       \
                for (int kt2 = 0; kt2 < 4; kt2++) {                                                     \
                    union { unsigned u[2]; bf16x4 v; } af;                                              \
                    af.u[0] = du0[kt2]; af.u[1] = du1[kt2];                                             \
                    osum[mt] = mfma16(af.v, vones4, osum[mt]);                                          \
                    _Pragma("unroll")                                                                   \
                    for (int nt = 0; nt < 4; nt++)                                                      \
                        o[mt][nt] = mfma16(af.v, vb4[kt2][nt], o[mt][nt]);                              \
                }                                                                                       \
            }                                                                                           \
        }                                                                                               \
    }

    for (int kt = 0; kt < 16; kt += 2) {
        ATTN_STEP(Ks0, Vs0, Ks1, Vs1, kt, 1);
        ATTN_STEP(Ks1, Vs1, Ks0, Vs0, kt + 1, (kt + 2 < 16));
    }
#undef ATTN_STEP

    // finalize: osum[mt][r] is the full row sum for q-row quad*4+r (replicated over l15)
    for (int mt = 0; mt < 2; mt++) {
        for (int r = 0; r < 4; r++) {
            float iv = __builtin_amdgcn_rcpf(osum[mt][r]);
            int q = q0 + w * 32 + mt * 16 + quad * 4 + r;
            size_t base = (rowbase + q) * 1024 + cbase;
            for (int nt = 0; nt < 4; nt++)
                out[base + nt * 16 + l15] = o[mt][nt][r] * iv;
        }
    }
}

extern "C" void kernel_launch(void* const* d_in, const int* in_sizes, int n_in,
                              void* d_out, int out_size, void* d_ws, size_t ws_size,
                              hipStream_t stream) {
    const float* hs = (const float*)d_in[0];
    const float* Wq = (const float*)d_in[1];
    const float* bq = (const float*)d_in[2];
    const float* Wk = (const float*)d_in[3];
    const float* bk = (const float*)d_in[4];
    const float* Wv = (const float*)d_in[5];
    const float* bv = (const float*)d_in[6];
    const float* Ws = (const float*)d_in[7];
    const float* bs = (const float*)d_in[8];
    float* outp = (float*)d_out;

    char* ws = (char*)d_ws;
    ushort* Qb    = (ushort*)(ws);                 //  8 MB
    ushort* Kb    = (ushort*)(ws + 8388608);       //  8 MB
    ushort* VtG   = (ushort*)(ws + 16777216);      //  8 MB (V transposed [bh][d][s])
    float*  sb    = (float* )(ws + 25165824);      //  4 MB
    ushort* hs_bf = (ushort*)(ws + 29360128);      //  8 MB
    ushort* Wq_bf = (ushort*)(ws + 37748736);      //  2 MB
    ushort* Wk_bf = (ushort*)(ws + 39845888);      //  2 MB
    ushort* Wv_bf = (ushort*)(ws + 41943040);      //  2 MB
    ushort* Ws_bf = (ushort*)(ws + 44040192);      // 0.5 MB -> total 44,564,480 B

    cast_all<<<dim3(3712), dim3(256), 0, stream>>>(hs, Wq, Wk, Wv, Ws,
                                                   hs_bf, Wq_bf, Wk_bf, Wv_bf, Ws_bf);
    fused_qkvs<<<dim3(832), dim3(256), 0, stream>>>(hs_bf, Wq_bf, Wk_bf, Wv_bf, Ws_bf,
                                                    bq, bk, bv, bs, Qb, Kb, VtG, sb);
    attn_kernel<<<dim3(512), dim3(256), 0, stream>>>(Qb, Kb, VtG, sb, outp);
}